// Round 2
// baseline (4711.762 us; speedup 1.0000x reference)
//
#include <hip/hip_runtime.h>
#include <hip/hip_bf16.h>
#include <math.h>

// Mamba block, correctness-first pipeline; bf16 at-rest intermediates,
// fp32 compute. Dims fixed: B=4, L=2048, dim=1024, d_inner=2048, d_state=16,
// d_conv=4, dt_rank=64. Rows = B*L = 8192.
//
// Workspace (~99 MiB): scale[8192] f32 | xz bf16 [8192,4096] | xc bf16
// [8192,2048] | dbc f32 [8192,96].  delta / gated-y alias the xi half
// (cols 0..2047) of xz, which is dead after the conv.

#define ROWS 8192
#define DIM 1024
#define DINNER 2048
#define DSTATE 16
#define DTRANK 64
#define LSEQ 2048

typedef __hip_bfloat16 bf16;

__device__ inline float ldf(const float* p) { return *p; }
__device__ inline float ldf(const bf16* p) { return __bfloat162float(*p); }
__device__ inline void stf(float* p, float v) { *p = v; }
__device__ inline void stf(bf16* p, float v) { *p = __float2bfloat16(v); }

// ---------------- RMSNorm row scales ----------------
__global__ __launch_bounds__(256)
void rms_scale_kernel(const float* __restrict__ x, float* __restrict__ scale) {
    int row = blockIdx.x;
    const float* xr = x + (long)row * DIM;
    float ss = 0.f;
    for (int i = threadIdx.x; i < DIM; i += 256) { float v = xr[i]; ss += v * v; }
    for (int off = 32; off > 0; off >>= 1) ss += __shfl_down(ss, off);
    __shared__ float red[4];
    if ((threadIdx.x & 63) == 0) red[threadIdx.x >> 6] = ss;
    __syncthreads();
    if (threadIdx.x == 0) {
        float tot = red[0] + red[1] + red[2] + red[3];
        scale[row] = rsqrtf(tot / DIM + 1e-5f);
    }
}

// ---------------- Generic tiled GEMM (fp32 compute) ----------------
// C[M,N] = A[M,K](lda) @ B[K,N](ldb). 64x64 tile, BK=16, 256 thr, 4x4 micro.
// RMS=1: A-element scaled by scale[row]*rmsw[k] (fused RMSNorm).
// EPI: 0=none, 1=softplus(acc+aux[col]), 2=acc+aux[row*ldc+col] (residual).
template <int EPI, int RMS, typename TA, typename TB, typename TC>
__global__ __launch_bounds__(256)
void gemm_kernel(const TA* __restrict__ A, int lda,
                 const TB* __restrict__ B, int ldb,
                 TC* __restrict__ C, int ldc,
                 int M, int N, int K,
                 const float* __restrict__ aux,
                 const float* __restrict__ scale,
                 const float* __restrict__ rmsw) {
    __shared__ float As[16][65];
    __shared__ float Bs[16][64];
    int tid = threadIdx.x;
    int tx = tid & 15, ty = tid >> 4;
    int row0 = blockIdx.y * 64;
    int col0 = blockIdx.x * 64;
    float acc[4][4] = {};
    int ar = tid >> 2;          // 0..63 (M % 64 == 0, rows always in-bounds)
    int ac = (tid & 3) * 4;     // k offset
    int bk = tid >> 4;          // 0..15
    int bc = (tid & 15) * 4;    // col offset

    float smul = RMS ? scale[row0 + ar] : 1.f;

    for (int k0 = 0; k0 < K; k0 += 16) {
        {
            const TA* ap = A + (long)(row0 + ar) * lda + k0 + ac;
#pragma unroll
            for (int t = 0; t < 4; ++t) {
                int gk = k0 + ac + t;
                float v = (gk < K) ? (RMS ? ldf(ap + t) * smul * rmsw[gk]
                                          : ldf(ap + t))
                                   : 0.f;
                As[ac + t][ar] = v;
            }
        }
        {
            int gk = k0 + bk;
            const TB* bp = B + (long)gk * ldb + col0 + bc;
#pragma unroll
            for (int t = 0; t < 4; ++t) {
                int gc = col0 + bc + t;
                Bs[bk][bc + t] = (gk < K && gc < N) ? ldf(bp + t) : 0.f;
            }
        }
        __syncthreads();
#pragma unroll
        for (int kk = 0; kk < 16; ++kk) {
            float a[4], b[4];
#pragma unroll
            for (int i = 0; i < 4; ++i) a[i] = As[kk][ty * 4 + i];
#pragma unroll
            for (int j = 0; j < 4; ++j) b[j] = Bs[kk][tx * 4 + j];
#pragma unroll
            for (int i = 0; i < 4; ++i)
#pragma unroll
                for (int j = 0; j < 4; ++j) acc[i][j] += a[i] * b[j];
        }
        __syncthreads();
    }
#pragma unroll
    for (int i = 0; i < 4; ++i) {
        int r = row0 + ty * 4 + i;
#pragma unroll
        for (int j = 0; j < 4; ++j) {
            int cidx = col0 + tx * 4 + j;
            if (cidx < N) {
                float v = acc[i][j];
                if (EPI == 1) {
                    v += aux[cidx];
                    v = (v > 20.f) ? v : log1pf(expf(v));
                } else if (EPI == 2) {
                    v += aux[(long)r * ldc + cidx];
                }
                stf(C + (long)r * ldc + cidx, v);
            }
        }
    }
}

// ---------------- causal depthwise conv (K=4) + SiLU ----------------
// in: xz bf16 [ROWS, 4096], xi = cols 0..2047. out: xc bf16 [ROWS, 2048]
__global__ __launch_bounds__(256)
void conv_silu_kernel(const bf16* __restrict__ xz, const float* __restrict__ cw,
                      const float* __restrict__ cb, bf16* __restrict__ out) {
    long idx = (long)blockIdx.x * 256 + threadIdx.x;   // [0, ROWS*DINNER)
    int c = (int)(idx & (DINNER - 1));
    long row = idx >> 11;
    int l = (int)(row & (LSEQ - 1));
    float acc = cb[c];
#pragma unroll
    for (int k = 0; k < 4; ++k) {
        int ll = l - 3 + k;
        if (ll >= 0)
            acc += __bfloat162float(xz[(row - 3 + k) * (2 * DINNER) + c]) * cw[c * 4 + k];
    }
    out[idx] = __float2bfloat16(acc / (1.f + expf(-acc)));
}

// ---------------- selective scan + D-skip + SiLU gate ----------------
// thread = (b, c, s); 16 lanes per channel, shfl_xor reduce over s.
// dio = xz base: delta at [row*4096 + c] (bf16), z at [row*4096 + 2048 + c].
// Gated y written in-place over delta (same wave reads before lane-0 write).
__global__ __launch_bounds__(256)
void scan_kernel(bf16* __restrict__ dio,
                 const bf16* __restrict__ xc,
                 const float* __restrict__ dbc,     // [ROWS,96]: dt|B|C
                 const float* __restrict__ A_log,
                 const float* __restrict__ Dp) {
    int tid = threadIdx.x;
    int s = tid & 15;
    int cloc = tid >> 4;                 // 0..15
    int b = blockIdx.x >> 7;             // 4 b x 128 ctiles
    int c = ((blockIdx.x & 127) << 4) + cloc;
    float Acs = -expf(A_log[c * DSTATE + s]);
    float Dc = Dp[c];
    float h = 0.f;
    long base_row = (long)b * LSEQ;
    for (int l = 0; l < LSEQ; ++l) {
        long row = base_row + l;
        float d = __bfloat162float(dio[row * 4096 + c]);
        float x_t = __bfloat162float(xc[row * DINNER + c]);
        float Bsv = dbc[row * 96 + 64 + s];
        float Csv = dbc[row * 96 + 80 + s];
        h = expf(d * Acs) * h + (d * x_t) * Bsv;
        float y = h * Csv;
        y += __shfl_xor(y, 1);
        y += __shfl_xor(y, 2);
        y += __shfl_xor(y, 4);
        y += __shfl_xor(y, 8);
        if (s == 0) {
            float z = __bfloat162float(dio[row * 4096 + 2048 + c]);
            float yv = (y + x_t * Dc) * (z / (1.f + expf(-z)));
            dio[row * 4096 + c] = __float2bfloat16(yv);
        }
    }
}

extern "C" void kernel_launch(void* const* d_in, const int* in_sizes, int n_in,
                              void* d_out, int out_size, void* d_ws, size_t ws_size,
                              hipStream_t stream) {
    const float* x        = (const float*)d_in[0];
    const float* rms_w    = (const float*)d_in[1];
    const float* in_proj  = (const float*)d_in[2];
    const float* conv_w   = (const float*)d_in[3];
    const float* conv_b   = (const float*)d_in[4];
    const float* x_proj   = (const float*)d_in[5];
    const float* dt_w     = (const float*)d_in[6];
    const float* dt_b     = (const float*)d_in[7];
    const float* A_log    = (const float*)d_in[8];
    const float* Dp       = (const float*)d_in[9];
    const float* out_proj = (const float*)d_in[10];
    float* out = (float*)d_out;

    float* ws = (float*)d_ws;
    float* scale = ws;                                   // 8192 f32 (32 KiB)
    bf16* xz = (bf16*)(ws + 8192);                       // 8192*4096 bf16 (64 MiB)
    bf16* xc = xz + (size_t)ROWS * 4096;                 // 8192*2048 bf16 (32 MiB)
    float* dbc = (float*)(xc + (size_t)ROWS * DINNER);   // 8192*96 f32 (3 MiB)
    // total ~99.05 MiB

    // 1. RMSNorm row scales
    rms_scale_kernel<<<ROWS, 256, 0, stream>>>(x, scale);
    // 2. xz = rmsnorm(x) @ in_proj   [8192,1024]@[1024,4096] -> bf16
    gemm_kernel<0, 1, float, float, bf16><<<dim3(4096 / 64, ROWS / 64), 256, 0, stream>>>(
        x, DIM, in_proj, 2 * DINNER, xz, 2 * DINNER, ROWS, 2 * DINNER, DIM,
        nullptr, scale, rms_w);
    // 3. causal conv + silu -> xc bf16
    conv_silu_kernel<<<(ROWS * DINNER) / 256, 256, 0, stream>>>(xz, conv_w, conv_b, xc);
    // 4. dbc = xc @ x_proj   [8192,2048]@[2048,96] -> f32
    gemm_kernel<0, 0, bf16, float, float><<<dim3(2, ROWS / 64), 256, 0, stream>>>(
        xc, DINNER, x_proj, 96, dbc, 96, ROWS, 96, DINNER, nullptr, nullptr, nullptr);
    // 5. delta = softplus(dbc[:,:64] @ dt_w + dt_b) -> bf16, aliased over xi cols of xz
    gemm_kernel<1, 0, float, float, bf16><<<dim3(DINNER / 64, ROWS / 64), 256, 0, stream>>>(
        dbc, 96, dt_w, DINNER, xz, 2 * DINNER, ROWS, DINNER, DTRANK, dt_b, nullptr, nullptr);
    // 6. selective scan + D-skip + gate (in-place over delta cols of xz)
    scan_kernel<<<4 * (DINNER / 16), 256, 0, stream>>>(xz, xc, dbc, A_log, Dp);
    // 7. out = x + y @ out_proj   [8192,2048]@[2048,1024] -> f32
    gemm_kernel<2, 0, bf16, float, float><<<dim3(DIM / 64, ROWS / 64), 256, 0, stream>>>(
        xz, 2 * DINNER, out_proj, DIM, out, DIM, ROWS, DIM, DINNER, x, nullptr, nullptr);
}

// Round 3
// 1513.466 us; speedup vs baseline: 3.1132x; 3.1132x over previous
//
#include <hip/hip_runtime.h>
#include <hip/hip_bf16.h>
#include <math.h>

// Mamba block. bf16 MFMA for the two large GEMMs; fp32 VALU for the small
// ones; bf16 at-rest intermediates. Dims fixed: B=4, L=2048, dim=1024,
// d_inner=2048, d_state=16, d_conv=4, dt_rank=64. Rows = B*L = 8192.

#define ROWS 8192
#define DIM 1024
#define DINNER 2048
#define DSTATE 16
#define DTRANK 64
#define LSEQ 2048

typedef unsigned short ushort;
typedef __attribute__((ext_vector_type(8))) short short8;
typedef __attribute__((ext_vector_type(4))) float float4v;

__device__ inline ushort f2bf(float f) {
    __hip_bfloat16 h = __float2bfloat16(f);
    return *reinterpret_cast<ushort*>(&h);
}
__device__ inline float bf2f(ushort u) {
    union { unsigned int i; float f; } w; w.i = ((unsigned int)u) << 16; return w.f;
}
__device__ inline float ldf(const float* p) { return *p; }
__device__ inline float ldf(const ushort* p) { return bf2f(*p); }

// ---------------- RMSNorm row scales ----------------
__global__ __launch_bounds__(256)
void rms_scale_kernel(const float* __restrict__ x, float* __restrict__ scale) {
    int row = blockIdx.x;
    const float* xr = x + (long)row * DIM;
    float ss = 0.f;
    for (int i = threadIdx.x; i < DIM; i += 256) { float v = xr[i]; ss += v * v; }
    for (int off = 32; off > 0; off >>= 1) ss += __shfl_down(ss, off);
    __shared__ float red[4];
    if ((threadIdx.x & 63) == 0) red[threadIdx.x >> 6] = ss;
    __syncthreads();
    if (threadIdx.x == 0) {
        float tot = red[0] + red[1] + red[2] + red[3];
        scale[row] = rsqrtf(tot / DIM + 1e-5f);
    }
}

// ---------------- fp32 [R][C] -> bf16 [C][R] transpose (32x32 LDS tiles) ----
__global__ __launch_bounds__(256)
void transpose_kernel(const float* __restrict__ in, ushort* __restrict__ outT,
                      int R, int C) {
    __shared__ float t[32][33];
    int tx = threadIdx.x & 31, ty = threadIdx.x >> 5;   // ty 0..7
    int bx = blockIdx.x, by = blockIdx.y;
#pragma unroll
    for (int k = 0; k < 4; ++k)
        t[ty + k * 8][tx] = in[(long)(by * 32 + ty + k * 8) * C + bx * 32 + tx];
    __syncthreads();
#pragma unroll
    for (int k = 0; k < 4; ++k)
        outT[(long)(bx * 32 + ty + k * 8) * R + by * 32 + tx] = f2bf(t[tx][ty + k * 8]);
}

// ---------------- bf16 MFMA GEMM ----------------
// C[M,N] = A[M,K] @ B[K,N], with Bt = B^T given row-major [N][K] bf16.
// 128x128 block tile, BK=32, 256 thr = 4 waves in 2x2, each wave 4x4 of
// 16x16x32 MFMA. M,N multiples of 128; K multiple of 32.
// ARMS=1: A is fp32, element scaled by scale[row]*rmsw[k] (fused RMSNorm).
// ARMS=0: A is bf16 (ushort), leading dim lda.
// EPI=0: store bf16. EPI=2: store f32 acc + aux[row*ldc+col] (residual).
template <int EPI, int ARMS>
__global__ __launch_bounds__(256)
void mfma_gemm(const void* __restrict__ Av, int lda,
               const ushort* __restrict__ Bt, int ldbt,
               void* __restrict__ Cv, int ldc,
               int M, int N, int K,
               const float* __restrict__ aux,
               const float* __restrict__ scale,
               const float* __restrict__ rmsw) {
    __shared__ __align__(16) ushort As[128][40];   // +8 pad: 2-way conflicts only
    __shared__ __align__(16) ushort Bs[128][40];
    int tid = threadIdx.x;
    int wave = tid >> 6, lane = tid & 63;
    int wm = wave >> 1, wn = wave & 1;
    int quad = lane >> 4, l16 = lane & 15;
    int row0 = blockIdx.y * 128, col0 = blockIdx.x * 128;

    int srow = tid >> 2;        // 0..63
    int sseg = tid & 3;         // 0..3 (8 elems each)

    float4v acc[4][4] = {};

    for (int k0 = 0; k0 < K; k0 += 32) {
        // stage A tile [128][32]
#pragma unroll
        for (int it = 0; it < 2; ++it) {
            int r = srow + it * 64;
            if (ARMS) {
                const float* ap = (const float*)Av + (long)(row0 + r) * lda + k0 + sseg * 8;
                float sm = scale[row0 + r];
                ushort tmp[8];
#pragma unroll
                for (int j = 0; j < 8; ++j)
                    tmp[j] = f2bf(ap[j] * sm * rmsw[k0 + sseg * 8 + j]);
                *reinterpret_cast<short8*>(&As[r][sseg * 8]) =
                    *reinterpret_cast<const short8*>(tmp);
            } else {
                const ushort* ap = (const ushort*)Av + (long)(row0 + r) * lda + k0 + sseg * 8;
                *reinterpret_cast<short8*>(&As[r][sseg * 8]) =
                    *reinterpret_cast<const short8*>(ap);
            }
        }
        // stage B tile: Bs[n_local][k_local] from Bt[col0+n][k0+k]
#pragma unroll
        for (int it = 0; it < 2; ++it) {
            int r = srow + it * 64;
            const ushort* bp = Bt + (long)(col0 + r) * ldbt + k0 + sseg * 8;
            *reinterpret_cast<short8*>(&Bs[r][sseg * 8]) =
                *reinterpret_cast<const short8*>(bp);
        }
        __syncthreads();

        short8 afrag[4], bfrag[4];
#pragma unroll
        for (int i = 0; i < 4; ++i)
            afrag[i] = *reinterpret_cast<const short8*>(&As[wm * 64 + i * 16 + l16][quad * 8]);
#pragma unroll
        for (int j = 0; j < 4; ++j)
            bfrag[j] = *reinterpret_cast<const short8*>(&Bs[wn * 64 + j * 16 + l16][quad * 8]);
#pragma unroll
        for (int i = 0; i < 4; ++i)
#pragma unroll
            for (int j = 0; j < 4; ++j)
                acc[i][j] = __builtin_amdgcn_mfma_f32_16x16x32_bf16(
                    afrag[i], bfrag[j], acc[i][j], 0, 0, 0);
        __syncthreads();
    }

    // epilogue: D[row=(quad*4+r)][col=l16] per 16x16 tile
#pragma unroll
    for (int i = 0; i < 4; ++i) {
#pragma unroll
        for (int j = 0; j < 4; ++j) {
            int rbase = row0 + wm * 64 + i * 16 + quad * 4;
            int c = col0 + wn * 64 + j * 16 + l16;
#pragma unroll
            for (int r = 0; r < 4; ++r) {
                float v = acc[i][j][r];
                long idx = (long)(rbase + r) * ldc + c;
                if (EPI == 2) {
                    ((float*)Cv)[idx] = v + aux[idx];
                } else {
                    ((ushort*)Cv)[idx] = f2bf(v);
                }
            }
        }
    }
}

// ---------------- fp32 tiled GEMM (small GEMMs) ----------------
// EPI: 0=none->f32, 1=softplus(acc+aux[col])->bf16
template <int EPI, typename TA, typename TC>
__global__ __launch_bounds__(256)
void gemm_kernel(const TA* __restrict__ A, int lda,
                 const float* __restrict__ B, int ldb,
                 TC* __restrict__ C, int ldc,
                 int M, int N, int K,
                 const float* __restrict__ aux) {
    __shared__ float As[16][65];
    __shared__ float Bs[16][64];
    int tid = threadIdx.x;
    int tx = tid & 15, ty = tid >> 4;
    int row0 = blockIdx.y * 64;
    int col0 = blockIdx.x * 64;
    float acc[4][4] = {};
    int ar = tid >> 2;
    int ac = (tid & 3) * 4;
    int bk = tid >> 4;
    int bc = (tid & 15) * 4;

    for (int k0 = 0; k0 < K; k0 += 16) {
        {
            const TA* ap = A + (long)(row0 + ar) * lda + k0 + ac;
#pragma unroll
            for (int t = 0; t < 4; ++t) {
                int gk = k0 + ac + t;
                As[ac + t][ar] = (gk < K) ? ldf(ap + t) : 0.f;
            }
        }
        {
            int gk = k0 + bk;
            const float* bp = B + (long)gk * ldb + col0 + bc;
#pragma unroll
            for (int t = 0; t < 4; ++t) {
                int gc = col0 + bc + t;
                Bs[bk][bc + t] = (gk < K && gc < N) ? bp[t] : 0.f;
            }
        }
        __syncthreads();
#pragma unroll
        for (int kk = 0; kk < 16; ++kk) {
            float a[4], b[4];
#pragma unroll
            for (int i = 0; i < 4; ++i) a[i] = As[kk][ty * 4 + i];
#pragma unroll
            for (int j = 0; j < 4; ++j) b[j] = Bs[kk][tx * 4 + j];
#pragma unroll
            for (int i = 0; i < 4; ++i)
#pragma unroll
                for (int j = 0; j < 4; ++j) acc[i][j] += a[i] * b[j];
        }
        __syncthreads();
    }
#pragma unroll
    for (int i = 0; i < 4; ++i) {
        int r = row0 + ty * 4 + i;
#pragma unroll
        for (int j = 0; j < 4; ++j) {
            int cidx = col0 + tx * 4 + j;
            if (cidx < N) {
                float v = acc[i][j];
                if (EPI == 1) {
                    v += aux[cidx];
                    v = (v > 20.f) ? v : log1pf(expf(v));
                    ((ushort*)C)[(long)r * ldc + cidx] = f2bf(v);
                } else {
                    ((float*)C)[(long)r * ldc + cidx] = v;
                }
            }
        }
    }
}

// ---------------- causal depthwise conv (K=4) + SiLU ----------------
__global__ __launch_bounds__(256)
void conv_silu_kernel(const ushort* __restrict__ xz, const float* __restrict__ cw,
                      const float* __restrict__ cb, ushort* __restrict__ out) {
    long idx = (long)blockIdx.x * 256 + threadIdx.x;   // [0, ROWS*DINNER)
    int c = (int)(idx & (DINNER - 1));
    long row = idx >> 11;
    int l = (int)(row & (LSEQ - 1));
    float acc = cb[c];
#pragma unroll
    for (int k = 0; k < 4; ++k) {
        int ll = l - 3 + k;
        if (ll >= 0)
            acc += bf2f(xz[(row - 3 + k) * (2 * DINNER) + c]) * cw[c * 4 + k];
    }
    out[idx] = f2bf(acc / (1.f + expf(-acc)));
}

// ---------------- selective scan + D-skip + SiLU gate ----------------
// thread = (b,c,s); 16 lanes/channel, shfl_xor reduce over s.
// dio = xz base: delta at [row*4096+c] (bf16), z at [row*4096+2048+c].
// L-loop unrolled by 4 with load batch up front for latency hiding.
__global__ __launch_bounds__(256)
void scan_kernel(ushort* __restrict__ dio,
                 const ushort* __restrict__ xc,
                 const float* __restrict__ dbc,     // [ROWS,96]: dt|B|C
                 const float* __restrict__ A_log,
                 const float* __restrict__ Dp) {
    int tid = threadIdx.x;
    int s = tid & 15;
    int cloc = tid >> 4;
    int b = blockIdx.x >> 7;
    int c = ((blockIdx.x & 127) << 4) + cloc;
    float Acs = -expf(A_log[c * DSTATE + s]);
    float Dc = Dp[c];
    float h = 0.f;
    long base_row = (long)b * LSEQ;
    for (int l = 0; l < LSEQ; l += 4) {
        float d[4], xt[4], Bv[4], Cvv[4], zv[4];
#pragma unroll
        for (int u = 0; u < 4; ++u) {
            long row = base_row + l + u;
            d[u]   = bf2f(dio[row * 4096 + c]);
            xt[u]  = bf2f(xc[row * DINNER + c]);
            Bv[u]  = dbc[row * 96 + 64 + s];
            Cvv[u] = dbc[row * 96 + 80 + s];
            zv[u]  = bf2f(dio[row * 4096 + 2048 + c]);
        }
#pragma unroll
        for (int u = 0; u < 4; ++u) {
            h = expf(d[u] * Acs) * h + (d[u] * xt[u]) * Bv[u];
            float y = h * Cvv[u];
            y += __shfl_xor(y, 1);
            y += __shfl_xor(y, 2);
            y += __shfl_xor(y, 4);
            y += __shfl_xor(y, 8);
            if (s == 0) {
                long row = base_row + l + u;
                float z = zv[u];
                float yv = (y + xt[u] * Dc) * (z / (1.f + expf(-z)));
                dio[row * 4096 + c] = f2bf(yv);
            }
        }
    }
}

extern "C" void kernel_launch(void* const* d_in, const int* in_sizes, int n_in,
                              void* d_out, int out_size, void* d_ws, size_t ws_size,
                              hipStream_t stream) {
    const float* x        = (const float*)d_in[0];
    const float* rms_w    = (const float*)d_in[1];
    const float* in_proj  = (const float*)d_in[2];
    const float* conv_w   = (const float*)d_in[3];
    const float* conv_b   = (const float*)d_in[4];
    const float* x_proj   = (const float*)d_in[5];
    const float* dt_w     = (const float*)d_in[6];
    const float* dt_b     = (const float*)d_in[7];
    const float* A_log    = (const float*)d_in[8];
    const float* Dp       = (const float*)d_in[9];
    const float* out_proj = (const float*)d_in[10];
    float* out = (float*)d_out;

    float* ws = (float*)d_ws;
    float* scale = ws;                                    // 8192 f32
    ushort* xz  = (ushort*)(ws + 8192);                   // [8192][4096] bf16 (64M)
    ushort* xc  = xz + (size_t)ROWS * 4096;               // [8192][2048] bf16 (32M)
    float*  dbc = (float*)(xc + (size_t)ROWS * DINNER);   // [8192][96] f32 (3M)
    ushort* bt1 = (ushort*)(dbc + (size_t)ROWS * 96);     // in_proj^T bf16 [4096][1024] (8M)
    ushort* bt2 = bt1 + (size_t)4096 * 1024;              // out_proj^T bf16 [1024][2048] (4M)
    // total ~111 MiB

    // 0. weight transposes -> bf16 B^T
    transpose_kernel<<<dim3(4096 / 32, 1024 / 32), 256, 0, stream>>>(in_proj, bt1, 1024, 4096);
    transpose_kernel<<<dim3(1024 / 32, 2048 / 32), 256, 0, stream>>>(out_proj, bt2, 2048, 1024);
    // 1. RMSNorm row scales
    rms_scale_kernel<<<ROWS, 256, 0, stream>>>(x, scale);
    // 2. xz = rmsnorm(x) @ in_proj  [8192,1024]@[1024,4096] -> bf16 (MFMA)
    mfma_gemm<0, 1><<<dim3(4096 / 128, ROWS / 128), 256, 0, stream>>>(
        x, DIM, bt1, 1024, xz, 4096, ROWS, 4096, DIM, nullptr, scale, rms_w);
    // 3. causal conv + silu -> xc bf16
    conv_silu_kernel<<<(ROWS * DINNER) / 256, 256, 0, stream>>>(xz, conv_w, conv_b, xc);
    // 4. dbc = xc @ x_proj  [8192,2048]@[2048,96] -> f32
    gemm_kernel<0, ushort, float><<<dim3(2, ROWS / 64), 256, 0, stream>>>(
        xc, DINNER, x_proj, 96, dbc, 96, ROWS, 96, DINNER, nullptr);
    // 5. delta = softplus(dbc[:,:64] @ dt_w + dt_b) -> bf16 over xi cols of xz
    gemm_kernel<1, float, ushort><<<dim3(DINNER / 64, ROWS / 64), 256, 0, stream>>>(
        dbc, 96, dt_w, DINNER, xz, 4096, ROWS, DINNER, DTRANK, dt_b);
    // 6. selective scan + D-skip + gate (in-place over delta cols of xz)
    scan_kernel<<<4 * (DINNER / 16), 256, 0, stream>>>(xz, xc, dbc, A_log, Dp);
    // 7. out = x + y @ out_proj  [8192,2048]@[2048,1024] -> f32 (MFMA)
    mfma_gemm<2, 0><<<dim3(DIM / 128, ROWS / 128), 256, 0, stream>>>(
        xz, 4096, bt2, DINNER, out, DIM, ROWS, DIM, DINNER, x, nullptr, nullptr);
}

// Round 4
// 626.793 us; speedup vs baseline: 7.5173x; 2.4146x over previous
//
#include <hip/hip_runtime.h>
#include <hip/hip_bf16.h>
#include <math.h>

// Mamba block. bf16 MFMA for all 4 GEMMs; chunked 3-phase parallel scan.
// Dims fixed: B=4, L=2048, dim=1024, d_inner=2048, d_state=16, d_conv=4,
// dt_rank=64. Rows = B*L = 8192.

#define ROWS 8192
#define DIM 1024
#define DINNER 2048
#define DSTATE 16
#define DTRANK 64
#define LSEQ 2048
#define NCHUNK 16
#define LCHUNK 128   // LSEQ/NCHUNK

typedef unsigned short ushort;
typedef __attribute__((ext_vector_type(8))) short short8;
typedef __attribute__((ext_vector_type(4))) float float4v;

__device__ inline ushort f2bf(float f) {
    __hip_bfloat16 h = __float2bfloat16(f);
    return *reinterpret_cast<ushort*>(&h);
}
__device__ inline float bf2f(ushort u) {
    union { unsigned int i; float f; } w; w.i = ((unsigned int)u) << 16; return w.f;
}

// ---------------- RMSNorm row scales ----------------
__global__ __launch_bounds__(256)
void rms_scale_kernel(const float* __restrict__ x, float* __restrict__ scale) {
    int row = blockIdx.x;
    const float* xr = x + (long)row * DIM;
    float ss = 0.f;
    for (int i = threadIdx.x; i < DIM; i += 256) { float v = xr[i]; ss += v * v; }
    for (int off = 32; off > 0; off >>= 1) ss += __shfl_down(ss, off);
    __shared__ float red[4];
    if ((threadIdx.x & 63) == 0) red[threadIdx.x >> 6] = ss;
    __syncthreads();
    if (threadIdx.x == 0) {
        float tot = red[0] + red[1] + red[2] + red[3];
        scale[row] = rsqrtf(tot / DIM + 1e-5f);
    }
}

// ---------------- fp32 [R][C] -> bf16 [C][R] transpose (32x32 LDS tiles) ----
__global__ __launch_bounds__(256)
void transpose_kernel(const float* __restrict__ in, ushort* __restrict__ outT,
                      int R, int C) {
    __shared__ float t[32][33];
    int tx = threadIdx.x & 31, ty = threadIdx.x >> 5;   // ty 0..7
    int bx = blockIdx.x, by = blockIdx.y;
#pragma unroll
    for (int k = 0; k < 4; ++k)
        t[ty + k * 8][tx] = in[(long)(by * 32 + ty + k * 8) * C + bx * 32 + tx];
    __syncthreads();
#pragma unroll
    for (int k = 0; k < 4; ++k)
        outT[(long)(bx * 32 + ty + k * 8) * R + by * 32 + tx] = f2bf(t[tx][ty + k * 8]);
}

// ---------------- bf16 MFMA GEMM ----------------
// C[M,N] = A[M,K] @ B[K,N], Bt = B^T row-major [N][K] bf16.
// 128x128 tile, BK=32, 256 thr = 4 waves (2x2), each wave 4x4 of 16x16x32.
// M % 128 == 0, N % 128 == 0 (tile), K % 32 == 0. Store guarded by c < Ncap.
// ARMS: 0 = A bf16; 1 = A fp32 scaled by scale[row]*rmsw[k] (fused RMSNorm);
//       2 = A fp32 plain convert.
// EPI: 0 = bf16 store; 1 = softplus(acc+aux[col]) -> bf16;
//      2 = acc + aux[row*ldc+col] -> f32 (residual); 3 = f32 store.
template <int EPI, int ARMS>
__global__ __launch_bounds__(256)
void mfma_gemm(const void* __restrict__ Av, int lda,
               const ushort* __restrict__ Bt, int ldbt,
               void* __restrict__ Cv, int ldc,
               int M, int N, int K,
               const float* __restrict__ aux,
               const float* __restrict__ scale,
               const float* __restrict__ rmsw,
               int Ncap) {
    __shared__ __align__(16) ushort As[128][40];   // +8 pad: 2-way conflicts only
    __shared__ __align__(16) ushort Bs[128][40];
    int tid = threadIdx.x;
    int wave = tid >> 6, lane = tid & 63;
    int wm = wave >> 1, wn = wave & 1;
    int quad = lane >> 4, l16 = lane & 15;
    int row0 = blockIdx.y * 128, col0 = blockIdx.x * 128;

    int srow = tid >> 2;        // 0..63
    int sseg = tid & 3;         // 0..3 (8 elems each)

    float4v acc[4][4] = {};

    for (int k0 = 0; k0 < K; k0 += 32) {
#pragma unroll
        for (int it = 0; it < 2; ++it) {
            int r = srow + it * 64;
            if (ARMS == 1) {
                const float* ap = (const float*)Av + (long)(row0 + r) * lda + k0 + sseg * 8;
                float sm = scale[row0 + r];
                ushort tmp[8];
#pragma unroll
                for (int j = 0; j < 8; ++j)
                    tmp[j] = f2bf(ap[j] * sm * rmsw[k0 + sseg * 8 + j]);
                *reinterpret_cast<short8*>(&As[r][sseg * 8]) =
                    *reinterpret_cast<const short8*>(tmp);
            } else if (ARMS == 2) {
                const float* ap = (const float*)Av + (long)(row0 + r) * lda + k0 + sseg * 8;
                ushort tmp[8];
#pragma unroll
                for (int j = 0; j < 8; ++j) tmp[j] = f2bf(ap[j]);
                *reinterpret_cast<short8*>(&As[r][sseg * 8]) =
                    *reinterpret_cast<const short8*>(tmp);
            } else {
                const ushort* ap = (const ushort*)Av + (long)(row0 + r) * lda + k0 + sseg * 8;
                *reinterpret_cast<short8*>(&As[r][sseg * 8]) =
                    *reinterpret_cast<const short8*>(ap);
            }
        }
#pragma unroll
        for (int it = 0; it < 2; ++it) {
            int r = srow + it * 64;
            const ushort* bp = Bt + (long)(col0 + r) * ldbt + k0 + sseg * 8;
            *reinterpret_cast<short8*>(&Bs[r][sseg * 8]) =
                *reinterpret_cast<const short8*>(bp);
        }
        __syncthreads();

        short8 afrag[4], bfrag[4];
#pragma unroll
        for (int i = 0; i < 4; ++i)
            afrag[i] = *reinterpret_cast<const short8*>(&As[wm * 64 + i * 16 + l16][quad * 8]);
#pragma unroll
        for (int j = 0; j < 4; ++j)
            bfrag[j] = *reinterpret_cast<const short8*>(&Bs[wn * 64 + j * 16 + l16][quad * 8]);
#pragma unroll
        for (int i = 0; i < 4; ++i)
#pragma unroll
            for (int j = 0; j < 4; ++j)
                acc[i][j] = __builtin_amdgcn_mfma_f32_16x16x32_bf16(
                    afrag[i], bfrag[j], acc[i][j], 0, 0, 0);
        __syncthreads();
    }

    // epilogue: D[row=(quad*4+r)][col=l16] per 16x16 tile
#pragma unroll
    for (int i = 0; i < 4; ++i) {
#pragma unroll
        for (int j = 0; j < 4; ++j) {
            int rbase = row0 + wm * 64 + i * 16 + quad * 4;
            int c = col0 + wn * 64 + j * 16 + l16;
#pragma unroll
            for (int r = 0; r < 4; ++r) {
                float v = acc[i][j][r];
                long idx = (long)(rbase + r) * ldc + c;
                if (c < Ncap) {
                    if (EPI == 2) {
                        ((float*)Cv)[idx] = v + aux[idx];
                    } else if (EPI == 3) {
                        ((float*)Cv)[idx] = v;
                    } else if (EPI == 1) {
                        v += aux[c];
                        v = (v > 20.f) ? v : log1pf(expf(v));
                        ((ushort*)Cv)[idx] = f2bf(v);
                    } else {
                        ((ushort*)Cv)[idx] = f2bf(v);
                    }
                }
            }
        }
    }
}

// ---------------- causal depthwise conv (K=4) + SiLU ----------------
__global__ __launch_bounds__(256)
void conv_silu_kernel(const ushort* __restrict__ xz, const float* __restrict__ cw,
                      const float* __restrict__ cb, ushort* __restrict__ out) {
    long idx = (long)blockIdx.x * 256 + threadIdx.x;   // [0, ROWS*DINNER)
    int c = (int)(idx & (DINNER - 1));
    long row = idx >> 11;
    int l = (int)(row & (LSEQ - 1));
    float4 w = ((const float4*)cw)[c];
    float wk[4] = {w.x, w.y, w.z, w.w};
    float acc = cb[c];
#pragma unroll
    for (int k = 0; k < 4; ++k) {
        int ll = l - 3 + k;
        if (ll >= 0)
            acc += bf2f(xz[(row - 3 + k) * (2 * DINNER) + c]) * wk[k];
    }
    out[idx] = f2bf(acc / (1.f + __expf(-acc)));
}

// ---------------- chunked selective scan ----------------
// thread = (b, c); 16 states in registers. G=NCHUNK chunks of LCHUNK steps.
// grid: (NCHUNK, DINNER/256, B), block 256.

// part1: chunk-local scan from h=0; emit chunk-end h[16] and sum(d).
__global__ __launch_bounds__(256)
void scan_part1(const ushort* __restrict__ xz,    // delta at [row*4096 + c]
                const ushort* __restrict__ xc,
                const float* __restrict__ dbc,    // [ROWS][96]: dt|B|C
                const float* __restrict__ A_log,
                float* __restrict__ hbuf,         // [B][G][16][2048]
                float* __restrict__ sdbuf) {      // [B][G][2048]
    int c = blockIdx.y * 256 + threadIdx.x;
    int b = blockIdx.z, g = blockIdx.x;
    float A[16];
#pragma unroll
    for (int s = 0; s < 16; ++s) A[s] = -__expf(A_log[c * 16 + s]);
    float h[16] = {};
    float sumd = 0.f;
    long row = (long)b * LSEQ + (long)g * LCHUNK;
    for (int l = 0; l < LCHUNK; ++l, ++row) {
        float d  = bf2f(xz[row * 4096 + c]);
        float xt = bf2f(xc[row * 2048 + c]);
        const float* __restrict__ bc = dbc + row * 96;
        sumd += d;
        float dx = d * xt;
#pragma unroll
        for (int s = 0; s < 16; ++s)
            h[s] = __expf(d * A[s]) * h[s] + dx * bc[64 + s];
    }
    long hb = ((long)(b * NCHUNK + g) * 16) * 2048 + c;
#pragma unroll
    for (int s = 0; s < 16; ++s) hbuf[hb + (long)s * 2048] = h[s];
    sdbuf[(long)(b * NCHUNK + g) * 2048 + c] = sumd;
}

// part2: serial combine over chunks; hbuf becomes h_in per chunk.
__global__ __launch_bounds__(256)
void scan_part2(float* __restrict__ hbuf, const float* __restrict__ sdbuf,
                const float* __restrict__ A_log) {
    int gl = blockIdx.x * 256 + threadIdx.x;   // 131072 threads
    int c = gl & 2047, s = (gl >> 11) & 15, b = gl >> 15;
    float A = -__expf(A_log[c * 16 + s]);
    float hrun = 0.f;
    for (int g = 0; g < NCHUNK; ++g) {
        long hi = ((long)(b * NCHUNK + g) * 16 + s) * 2048 + c;
        float hout = hbuf[hi];
        float sd = sdbuf[(long)(b * NCHUNK + g) * 2048 + c];
        hbuf[hi] = hrun;                   // h_in for chunk g
        hrun = __expf(A * sd) * hrun + hout;
    }
}

// part3: re-scan chunk from h_in; y = sum_s h*C; D-skip + SiLU gate; write bf16.
__global__ __launch_bounds__(256)
void scan_part3(ushort* __restrict__ xz,          // delta in / gated y out; z at +2048
                const ushort* __restrict__ xc,
                const float* __restrict__ dbc,
                const float* __restrict__ A_log,
                const float* __restrict__ Dp,
                const float* __restrict__ hbuf) {
    int c = blockIdx.y * 256 + threadIdx.x;
    int b = blockIdx.z, g = blockIdx.x;
    float A[16], h[16];
#pragma unroll
    for (int s = 0; s < 16; ++s) A[s] = -__expf(A_log[c * 16 + s]);
    long hb = ((long)(b * NCHUNK + g) * 16) * 2048 + c;
#pragma unroll
    for (int s = 0; s < 16; ++s) h[s] = hbuf[hb + (long)s * 2048];
    float Dc = Dp[c];
    long row = (long)b * LSEQ + (long)g * LCHUNK;
    for (int l = 0; l < LCHUNK; ++l, ++row) {
        float d  = bf2f(xz[row * 4096 + c]);
        float xt = bf2f(xc[row * 2048 + c]);
        float z  = bf2f(xz[row * 4096 + 2048 + c]);
        const float* __restrict__ bc = dbc + row * 96;
        float dx = d * xt;
        float y = 0.f;
#pragma unroll
        for (int s = 0; s < 16; ++s) {
            h[s] = __expf(d * A[s]) * h[s] + dx * bc[64 + s];
            y += h[s] * bc[80 + s];
        }
        float yv = (y + xt * Dc) * (z / (1.f + __expf(-z)));
        xz[row * 4096 + c] = f2bf(yv);
    }
}

extern "C" void kernel_launch(void* const* d_in, const int* in_sizes, int n_in,
                              void* d_out, int out_size, void* d_ws, size_t ws_size,
                              hipStream_t stream) {
    const float* x        = (const float*)d_in[0];
    const float* rms_w    = (const float*)d_in[1];
    const float* in_proj  = (const float*)d_in[2];
    const float* conv_w   = (const float*)d_in[3];
    const float* conv_b   = (const float*)d_in[4];
    const float* x_proj   = (const float*)d_in[5];
    const float* dt_w     = (const float*)d_in[6];
    const float* dt_b     = (const float*)d_in[7];
    const float* A_log    = (const float*)d_in[8];
    const float* Dp       = (const float*)d_in[9];
    const float* out_proj = (const float*)d_in[10];
    float* out = (float*)d_out;

    char* p = (char*)d_ws;
    float* scale = (float*)p;                 p += 8192 * 4;                 // 32 KB
    ushort* xz  = (ushort*)p;                 p += (size_t)ROWS * 4096 * 2;  // 64 MB
    ushort* xc  = (ushort*)p;                 p += (size_t)ROWS * 2048 * 2;  // 32 MB
    float*  dbc = (float*)p;                  p += (size_t)ROWS * 96 * 4;    // 3 MB
    ushort* bt1 = (ushort*)p;                 p += (size_t)4096 * 1024 * 2;  // 8 MB
    ushort* bt2 = (ushort*)p;                 p += (size_t)1024 * 2048 * 2;  // 4 MB
    ushort* bt3 = (ushort*)p;                 p += (size_t)128 * 2048 * 2;   // 512 KB
    ushort* bt4 = (ushort*)p;                 p += (size_t)2048 * 64 * 2;    // 256 KB
    float* hbuf = (float*)p;                  p += (size_t)4 * NCHUNK * 16 * 2048 * 4; // 8 MB
    float* sdbuf = (float*)p;                 p += (size_t)4 * NCHUNK * 2048 * 4;      // 512 KB
    // total ~120.3 MiB

    // 0. weight transposes -> bf16 B^T
    transpose_kernel<<<dim3(4096 / 32, 1024 / 32), 256, 0, stream>>>(in_proj, bt1, 1024, 4096);
    transpose_kernel<<<dim3(1024 / 32, 2048 / 32), 256, 0, stream>>>(out_proj, bt2, 2048, 1024);
    transpose_kernel<<<dim3(96 / 32, 2048 / 32), 256, 0, stream>>>(x_proj, bt3, 2048, 96);
    transpose_kernel<<<dim3(2048 / 32, 64 / 32), 256, 0, stream>>>(dt_w, bt4, 64, 2048);
    // 1. RMSNorm row scales
    rms_scale_kernel<<<ROWS, 256, 0, stream>>>(x, scale);
    // 2. xz = rmsnorm(x) @ in_proj  [8192,1024]@[1024,4096] -> bf16 (MFMA)
    mfma_gemm<0, 1><<<dim3(4096 / 128, ROWS / 128), 256, 0, stream>>>(
        x, DIM, bt1, 1024, xz, 4096, ROWS, 4096, DIM, nullptr, scale, rms_w, 4096);
    // 3. causal conv + silu -> xc bf16
    conv_silu_kernel<<<(ROWS * DINNER) / 256, 256, 0, stream>>>(xz, conv_w, conv_b, xc);
    // 4. dbc = xc @ x_proj  [8192,2048]@[2048,96] -> f32 (MFMA, N padded to 128)
    mfma_gemm<3, 0><<<dim3(1, ROWS / 128), 256, 0, stream>>>(
        xc, DINNER, bt3, 2048, dbc, 96, ROWS, 128, DINNER, nullptr, nullptr, nullptr, 96);
    // 5. delta = softplus(dbc[:,:64] @ dt_w + dt_b) -> bf16 over xi cols of xz (MFMA)
    mfma_gemm<1, 2><<<dim3(2048 / 128, ROWS / 128), 256, 0, stream>>>(
        dbc, 96, bt4, 64, xz, 4096, ROWS, 2048, DTRANK, dt_b, nullptr, nullptr, 2048);
    // 6. chunked selective scan
    scan_part1<<<dim3(NCHUNK, DINNER / 256, 4), 256, 0, stream>>>(
        xz, xc, dbc, A_log, hbuf, sdbuf);
    scan_part2<<<512, 256, 0, stream>>>(hbuf, sdbuf, A_log);
    scan_part3<<<dim3(NCHUNK, DINNER / 256, 4), 256, 0, stream>>>(
        xz, xc, dbc, A_log, Dp, hbuf);
    // 7. out = x + y @ out_proj  [8192,2048]@[2048,1024] -> f32 (MFMA)
    mfma_gemm<2, 0><<<dim3(DIM / 128, ROWS / 128), 256, 0, stream>>>(
        xz, 4096, bt2, DINNER, out, DIM, ROWS, DIM, DINNER, x, nullptr, nullptr, 1024);
}

// Round 5
// 588.347 us; speedup vs baseline: 8.0085x; 1.0653x over previous
//
#include <hip/hip_runtime.h>
#include <hip/hip_bf16.h>
#include <math.h>

// Mamba block. m97-style DMA-staged bf16 MFMA GEMMs (global_load_lds w=16)
// for in_proj / x_proj / out_proj; VALU-staged MFMA for the tiny dt GEMM;
// chunked 3-phase parallel scan. Dims fixed: B=4, L=2048, dim=1024,
// d_inner=2048, d_state=16, d_conv=4, dt_rank=64. Rows = B*L = 8192.

#define ROWS 8192
#define DIM 1024
#define DINNER 2048
#define DSTATE 16
#define DTRANK 64
#define LSEQ 2048
#define NCHUNK 16
#define LCHUNK 128   // LSEQ/NCHUNK

typedef unsigned short ushort;
typedef __attribute__((ext_vector_type(8))) short short8;
typedef __attribute__((ext_vector_type(4))) float float4v;

__device__ inline ushort f2bf(float f) {
    __hip_bfloat16 h = __float2bfloat16(f);
    return *reinterpret_cast<ushort*>(&h);
}
__device__ inline float bf2f(ushort u) {
    union { unsigned int i; float f; } w; w.i = ((unsigned int)u) << 16; return w.f;
}

// async global->LDS DMA, 16 B/lane. lds dest = wave-uniform base + lane*16.
__device__ inline void dma16(const void* g, void* l) {
    __builtin_amdgcn_global_load_lds(
        (const __attribute__((address_space(1))) unsigned int*)g,
        (__attribute__((address_space(3))) unsigned int*)l, 16, 0, 0);
}

// ---------------- fused RMSNorm -> bf16 (folds rms_w) ----------------
__global__ __launch_bounds__(256)
void rmsnorm_bf16_kernel(const float* __restrict__ x, const float* __restrict__ w,
                         ushort* __restrict__ xn) {
    int row = blockIdx.x;
    float4 xv = ((const float4*)(x + (long)row * DIM))[threadIdx.x];
    float ss = xv.x * xv.x + xv.y * xv.y + xv.z * xv.z + xv.w * xv.w;
    for (int off = 32; off > 0; off >>= 1) ss += __shfl_down(ss, off);
    __shared__ float red[4];
    if ((threadIdx.x & 63) == 0) red[threadIdx.x >> 6] = ss;
    __syncthreads();
    float scale = rsqrtf((red[0] + red[1] + red[2] + red[3]) / DIM + 1e-5f);
    float4 wv = ((const float4*)w)[threadIdx.x];
    ushort4 ov;
    ov.x = f2bf(xv.x * scale * wv.x);
    ov.y = f2bf(xv.y * scale * wv.y);
    ov.z = f2bf(xv.z * scale * wv.z);
    ov.w = f2bf(xv.w * scale * wv.w);
    ((ushort4*)xn)[(long)row * 256 + threadIdx.x] = ov;
}

// ---------------- fp32 [R][C] -> bf16 [C][R] transpose (32x32 LDS tiles) ----
__global__ __launch_bounds__(256)
void transpose_kernel(const float* __restrict__ in, ushort* __restrict__ outT,
                      int R, int C) {
    __shared__ float t[32][33];
    int tx = threadIdx.x & 31, ty = threadIdx.x >> 5;   // ty 0..7
    int bx = blockIdx.x, by = blockIdx.y;
#pragma unroll
    for (int k = 0; k < 4; ++k)
        t[ty + k * 8][tx] = in[(long)(by * 32 + ty + k * 8) * C + bx * 32 + tx];
    __syncthreads();
#pragma unroll
    for (int k = 0; k < 4; ++k)
        outT[(long)(bx * 32 + ty + k * 8) * R + by * 32 + tx] = f2bf(t[tx][ty + k * 8]);
}

// ---------------- DMA-staged bf16 MFMA GEMM (m97 structure) ----------------
// C[M,N] = A[M,K] @ B[K,N]; A bf16 [M][lda], Bt = B^T bf16 [N][ldbt].
// 128x128 tile, BK=32, 256 thr = 4 waves (2x2), wave does 4x4 of 16x16x32.
// LDS tiles [128][32] un-padded, filled by global_load_lds in lane order.
// EPI: 0 = bf16 store; 2 = acc + aux[row*ldc+col] -> f32; 3 = f32 store.
template <int EPI>
__global__ __launch_bounds__(256)
void mfma_gemm_dma(const ushort* __restrict__ A, int lda,
                   const ushort* __restrict__ Bt, int ldbt,
                   void* __restrict__ Cv, int ldc, int K,
                   const float* __restrict__ aux, int Ncap) {
    __shared__ __align__(16) ushort As[128][32];
    __shared__ __align__(16) ushort Bs[128][32];
    int tid = threadIdx.x;
    int wave = tid >> 6, lane = tid & 63;
    int wm = wave >> 1, wn = wave & 1;
    int quad = lane >> 4, l16 = lane & 15;
    int row0 = blockIdx.y * 128, col0 = blockIdx.x * 128;

    // DMA mapping: seg = wave*2+i covers rows [seg*16, seg*16+16);
    // lane l -> row seg*16 + l/4, k-seg (l%4)*8 (16 B).
    int r0 = (wave * 2 + 0) * 16 + (lane >> 2);
    int r1 = (wave * 2 + 1) * 16 + (lane >> 2);
    int ks = (lane & 3) * 8;
    const ushort* a0 = A + (long)(row0 + r0) * lda + ks;
    const ushort* a1 = A + (long)(row0 + r1) * lda + ks;
    const ushort* b0 = Bt + (long)(col0 + r0) * ldbt + ks;
    const ushort* b1 = Bt + (long)(col0 + r1) * ldbt + ks;
    ushort* lA0 = &As[(wave * 2 + 0) * 16][0];
    ushort* lA1 = &As[(wave * 2 + 1) * 16][0];
    ushort* lB0 = &Bs[(wave * 2 + 0) * 16][0];
    ushort* lB1 = &Bs[(wave * 2 + 1) * 16][0];

    float4v acc[4][4] = {};

    for (int k0 = 0; k0 < K; k0 += 32) {
        dma16(a0 + k0, lA0);
        dma16(a1 + k0, lA1);
        dma16(b0 + k0, lB0);
        dma16(b1 + k0, lB1);
        __syncthreads();   // drains vmcnt (global_load_lds) before LDS reads

        short8 afrag[4], bfrag[4];
#pragma unroll
        for (int i = 0; i < 4; ++i)
            afrag[i] = *reinterpret_cast<const short8*>(&As[wm * 64 + i * 16 + l16][quad * 8]);
#pragma unroll
        for (int j = 0; j < 4; ++j)
            bfrag[j] = *reinterpret_cast<const short8*>(&Bs[wn * 64 + j * 16 + l16][quad * 8]);
#pragma unroll
        for (int i = 0; i < 4; ++i)
#pragma unroll
            for (int j = 0; j < 4; ++j)
                acc[i][j] = __builtin_amdgcn_mfma_f32_16x16x32_bf16(
                    afrag[i], bfrag[j], acc[i][j], 0, 0, 0);
        __syncthreads();   // LDS reads done before next tile's DMA overwrites
    }

    // epilogue: D[row = quad*4 + r][col = l16] per 16x16 tile
#pragma unroll
    for (int i = 0; i < 4; ++i) {
#pragma unroll
        for (int j = 0; j < 4; ++j) {
            int rbase = row0 + wm * 64 + i * 16 + quad * 4;
            int c = col0 + wn * 64 + j * 16 + l16;
#pragma unroll
            for (int r = 0; r < 4; ++r) {
                float v = acc[i][j][r];
                long idx = (long)(rbase + r) * ldc + c;
                if (c < Ncap) {
                    if (EPI == 2)      ((float*)Cv)[idx] = v + aux[idx];
                    else if (EPI == 3) ((float*)Cv)[idx] = v;
                    else               ((ushort*)Cv)[idx] = f2bf(v);
                }
            }
        }
    }
}

// ---------------- VALU-staged MFMA GEMM for dt (A fp32, K=64) ----------------
// delta = softplus(dbc[:, :64] @ dt_w + dt_b) -> bf16 into xz xi-cols.
__global__ __launch_bounds__(256)
void mfma_gemm_dt(const float* __restrict__ A, int lda,
                  const ushort* __restrict__ Bt, int ldbt,
                  ushort* __restrict__ C, int ldc, int K,
                  const float* __restrict__ aux) {
    __shared__ __align__(16) ushort As[128][40];
    __shared__ __align__(16) ushort Bs[128][40];
    int tid = threadIdx.x;
    int wave = tid >> 6, lane = tid & 63;
    int wm = wave >> 1, wn = wave & 1;
    int quad = lane >> 4, l16 = lane & 15;
    int row0 = blockIdx.y * 128, col0 = blockIdx.x * 128;
    int srow = tid >> 2;
    int sseg = tid & 3;

    float4v acc[4][4] = {};

    for (int k0 = 0; k0 < K; k0 += 32) {
#pragma unroll
        for (int it = 0; it < 2; ++it) {
            int r = srow + it * 64;
            const float* ap = A + (long)(row0 + r) * lda + k0 + sseg * 8;
            ushort tmp[8];
#pragma unroll
            for (int j = 0; j < 8; ++j) tmp[j] = f2bf(ap[j]);
            *reinterpret_cast<short8*>(&As[r][sseg * 8]) =
                *reinterpret_cast<const short8*>(tmp);
            const ushort* bp = Bt + (long)(col0 + r) * ldbt + k0 + sseg * 8;
            *reinterpret_cast<short8*>(&Bs[r][sseg * 8]) =
                *reinterpret_cast<const short8*>(bp);
        }
        __syncthreads();
        short8 afrag[4], bfrag[4];
#pragma unroll
        for (int i = 0; i < 4; ++i)
            afrag[i] = *reinterpret_cast<const short8*>(&As[wm * 64 + i * 16 + l16][quad * 8]);
#pragma unroll
        for (int j = 0; j < 4; ++j)
            bfrag[j] = *reinterpret_cast<const short8*>(&Bs[wn * 64 + j * 16 + l16][quad * 8]);
#pragma unroll
        for (int i = 0; i < 4; ++i)
#pragma unroll
            for (int j = 0; j < 4; ++j)
                acc[i][j] = __builtin_amdgcn_mfma_f32_16x16x32_bf16(
                    afrag[i], bfrag[j], acc[i][j], 0, 0, 0);
        __syncthreads();
    }
#pragma unroll
    for (int i = 0; i < 4; ++i) {
#pragma unroll
        for (int j = 0; j < 4; ++j) {
            int rbase = row0 + wm * 64 + i * 16 + quad * 4;
            int c = col0 + wn * 64 + j * 16 + l16;
#pragma unroll
            for (int r = 0; r < 4; ++r) {
                float v = acc[i][j][r] + aux[c];
                v = (v > 20.f) ? v : log1pf(expf(v));
                C[(long)(rbase + r) * ldc + c] = f2bf(v);
            }
        }
    }
}

// ---------------- causal depthwise conv (K=4) + SiLU, 8 ch/thread ----------
__global__ __launch_bounds__(256)
void conv_silu_kernel(const ushort* __restrict__ xz, const float* __restrict__ cw,
                      const float* __restrict__ cb, ushort* __restrict__ out) {
    long t = (long)blockIdx.x * 256 + threadIdx.x;   // ROWS*256 threads
    int c0 = (int)(t & 255) << 3;
    long row = t >> 8;
    int l = (int)(row & (LSEQ - 1));
    short8 v[4];
#pragma unroll
    for (int k = 0; k < 4; ++k) {
        int ll = l - 3 + k;
        if (ll >= 0) v[k] = *(const short8*)&xz[(row - 3 + k) * 4096 + c0];
        else { short8 z = {0, 0, 0, 0, 0, 0, 0, 0}; v[k] = z; }
    }
    ushort o[8];
#pragma unroll
    for (int j = 0; j < 8; ++j) {
        float4 w = ((const float4*)cw)[c0 + j];
        float acc = cb[c0 + j];
        acc += bf2f((ushort)v[0][j]) * w.x;
        acc += bf2f((ushort)v[1][j]) * w.y;
        acc += bf2f((ushort)v[2][j]) * w.z;
        acc += bf2f((ushort)v[3][j]) * w.w;
        acc = acc / (1.f + __expf(-acc));
        o[j] = f2bf(acc);
    }
    *(short8*)&out[(long)row * 2048 + c0] = *(const short8*)o;
}

// ---------------- chunked selective scan ----------------
// part1: chunk-local scan from h=0; emit chunk-end h[16] and sum(d).
__global__ __launch_bounds__(256)
void scan_part1(const ushort* __restrict__ xz,    // delta at [row*4096 + c]
                const ushort* __restrict__ xc,
                const float* __restrict__ dbc,    // [ROWS][96]: dt|B|C
                const float* __restrict__ A_log,
                float* __restrict__ hbuf,         // [B][G][16][2048]
                float* __restrict__ sdbuf) {      // [B][G][2048]
    int c = blockIdx.y * 256 + threadIdx.x;
    int b = blockIdx.z, g = blockIdx.x;
    float A[16];
#pragma unroll
    for (int s = 0; s < 16; ++s) A[s] = -__expf(A_log[c * 16 + s]);
    float h[16] = {};
    float sumd = 0.f;
    long row = (long)b * LSEQ + (long)g * LCHUNK;
    for (int l = 0; l < LCHUNK; ++l, ++row) {
        float d  = bf2f(xz[row * 4096 + c]);
        float xt = bf2f(xc[row * 2048 + c]);
        const float* __restrict__ bc = dbc + row * 96;
        sumd += d;
        float dx = d * xt;
#pragma unroll
        for (int s = 0; s < 16; ++s)
            h[s] = __expf(d * A[s]) * h[s] + dx * bc[64 + s];
    }
    long hb = ((long)(b * NCHUNK + g) * 16) * 2048 + c;
#pragma unroll
    for (int s = 0; s < 16; ++s) hbuf[hb + (long)s * 2048] = h[s];
    sdbuf[(long)(b * NCHUNK + g) * 2048 + c] = sumd;
}

// part2: serial combine over chunks; hbuf becomes h_in per chunk.
__global__ __launch_bounds__(256)
void scan_part2(float* __restrict__ hbuf, const float* __restrict__ sdbuf,
                const float* __restrict__ A_log) {
    int gl = blockIdx.x * 256 + threadIdx.x;   // 131072 threads
    int c = gl & 2047, s = (gl >> 11) & 15, b = gl >> 15;
    float A = -__expf(A_log[c * 16 + s]);
    float hrun = 0.f;
    for (int g = 0; g < NCHUNK; ++g) {
        long hi = ((long)(b * NCHUNK + g) * 16 + s) * 2048 + c;
        float hout = hbuf[hi];
        float sd = sdbuf[(long)(b * NCHUNK + g) * 2048 + c];
        hbuf[hi] = hrun;                   // h_in for chunk g
        hrun = __expf(A * sd) * hrun + hout;
    }
}

// part3: re-scan chunk from h_in; y = sum_s h*C; D-skip + SiLU gate; bf16 out.
__global__ __launch_bounds__(256)
void scan_part3(ushort* __restrict__ xz,          // delta in / gated y out; z at +2048
                const ushort* __restrict__ xc,
                const float* __restrict__ dbc,
                const float* __restrict__ A_log,
                const float* __restrict__ Dp,
                const float* __restrict__ hbuf) {
    int c = blockIdx.y * 256 + threadIdx.x;
    int b = blockIdx.z, g = blockIdx.x;
    float A[16], h[16];
#pragma unroll
    for (int s = 0; s < 16; ++s) A[s] = -__expf(A_log[c * 16 + s]);
    long hb = ((long)(b * NCHUNK + g) * 16) * 2048 + c;
#pragma unroll
    for (int s = 0; s < 16; ++s) h[s] = hbuf[hb + (long)s * 2048];
    float Dc = Dp[c];
    long row = (long)b * LSEQ + (long)g * LCHUNK;
    for (int l = 0; l < LCHUNK; ++l, ++row) {
        float d  = bf2f(xz[row * 4096 + c]);
        float xt = bf2f(xc[row * 2048 + c]);
        float z  = bf2f(xz[row * 4096 + 2048 + c]);
        const float* __restrict__ bc = dbc + row * 96;
        float dx = d * xt;
        float y = 0.f;
#pragma unroll
        for (int s = 0; s < 16; ++s) {
            h[s] = __expf(d * A[s]) * h[s] + dx * bc[64 + s];
            y += h[s] * bc[80 + s];
        }
        float yv = (y + xt * Dc) * (z / (1.f + __expf(-z)));
        xz[row * 4096 + c] = f2bf(yv);
    }
}

extern "C" void kernel_launch(void* const* d_in, const int* in_sizes, int n_in,
                              void* d_out, int out_size, void* d_ws, size_t ws_size,
                              hipStream_t stream) {
    const float* x        = (const float*)d_in[0];
    const float* rms_w    = (const float*)d_in[1];
    const float* in_proj  = (const float*)d_in[2];
    const float* conv_w   = (const float*)d_in[3];
    const float* conv_b   = (const float*)d_in[4];
    const float* x_proj   = (const float*)d_in[5];
    const float* dt_w     = (const float*)d_in[6];
    const float* dt_b     = (const float*)d_in[7];
    const float* A_log    = (const float*)d_in[8];
    const float* Dp       = (const float*)d_in[9];
    const float* out_proj = (const float*)d_in[10];
    float* out = (float*)d_out;

    char* p = (char*)d_ws;
    ushort* xz  = (ushort*)p;   p += (size_t)ROWS * 4096 * 2;   // 64 MB
    ushort* xc  = (ushort*)p;   p += (size_t)ROWS * 2048 * 2;   // 32 MB
    float*  dbc = (float*)p;    p += (size_t)ROWS * 96 * 4;     // 3 MB
    ushort* bt1 = (ushort*)p;   p += (size_t)4096 * 1024 * 2;   // 8 MB  in_proj^T
    ushort* bt2 = (ushort*)p;   p += (size_t)1024 * 2048 * 2;   // 4 MB  out_proj^T
    ushort* bt3 = (ushort*)p;   p += (size_t)128 * 2048 * 2;    // 512 KB x_proj^T (96 used)
    ushort* bt4 = (ushort*)p;   p += (size_t)2048 * 64 * 2;     // 256 KB dt_w^T
    ushort* xn  = (ushort*)p;   p += (size_t)ROWS * 1024 * 2;   // 16 MB (dead after in_proj)
    float* hbuf  = (float*)xn;                                  // 8 MB   overlay on xn
    float* sdbuf = (float*)xn + (size_t)4 * NCHUNK * 16 * 2048; // 512 KB overlay on xn
    // total ~127.8 MiB

    // 0. weight transposes -> bf16 B^T
    transpose_kernel<<<dim3(4096 / 32, 1024 / 32), 256, 0, stream>>>(in_proj, bt1, 1024, 4096);
    transpose_kernel<<<dim3(1024 / 32, 2048 / 32), 256, 0, stream>>>(out_proj, bt2, 2048, 1024);
    transpose_kernel<<<dim3(96 / 32, 2048 / 32), 256, 0, stream>>>(x_proj, bt3, 2048, 96);
    transpose_kernel<<<dim3(2048 / 32, 64 / 32), 256, 0, stream>>>(dt_w, bt4, 64, 2048);
    // 1. RMSNorm -> xn bf16 (folds rms_w)
    rmsnorm_bf16_kernel<<<ROWS, 256, 0, stream>>>(x, rms_w, xn);
    // 2. xz = xn @ in_proj  [8192,1024]@[1024,4096] -> bf16 (DMA MFMA)
    mfma_gemm_dma<0><<<dim3(4096 / 128, ROWS / 128), 256, 0, stream>>>(
        xn, DIM, bt1, 1024, xz, 4096, DIM, nullptr, 4096);
    // 3. causal conv + silu -> xc bf16
    conv_silu_kernel<<<ROWS, 256, 0, stream>>>(xz, conv_w, conv_b, xc);
    // 4. dbc = xc @ x_proj  [8192,2048]@[2048,96] -> f32 (DMA MFMA, N pad 128)
    mfma_gemm_dma<3><<<dim3(1, ROWS / 128), 256, 0, stream>>>(
        xc, DINNER, bt3, 2048, dbc, 96, DINNER, nullptr, 96);
    // 5. delta = softplus(dbc[:,:64] @ dt_w + dt_b) -> bf16 over xi cols of xz
    mfma_gemm_dt<<<dim3(2048 / 128, ROWS / 128), 256, 0, stream>>>(
        dbc, 96, bt4, 64, xz, 4096, DTRANK, dt_b);
    // 6. chunked selective scan (hbuf/sdbuf overlay xn, dead by now)
    scan_part1<<<dim3(NCHUNK, DINNER / 256, 4), 256, 0, stream>>>(
        xz, xc, dbc, A_log, hbuf, sdbuf);
    scan_part2<<<512, 256, 0, stream>>>(hbuf, sdbuf, A_log);
    scan_part3<<<dim3(NCHUNK, DINNER / 256, 4), 256, 0, stream>>>(
        xz, xc, dbc, A_log, Dp, hbuf);
    // 7. out = x + y @ out_proj  [8192,2048]@[2048,1024] -> f32 (DMA MFMA)
    mfma_gemm_dma<2><<<dim3(DIM / 128, ROWS / 128), 256, 0, stream>>>(
        xz, 4096, bt2, DINNER, out, DIM, DINNER, x, 1024);
}

// Round 6
// 561.804 us; speedup vs baseline: 8.3868x; 1.0472x over previous
//
#include <hip/hip_runtime.h>
#include <hip/hip_bf16.h>
#include <math.h>

// Mamba block. 8 launches: prep(transposes+rmsnorm+zero) | in_proj DMA-MFMA |
// x_proj MFMA w/ conv+silu fused into A-staging (split-K, atomicAdd) |
// dt MFMA | scan part1/2/3 (conv fused via rolling window) | out_proj DMA-MFMA.
// Dims fixed: B=4, L=2048, dim=1024, d_inner=2048, d_state=16, d_conv=4,
// dt_rank=64. Rows = B*L = 8192.

#define ROWS 8192
#define DIM 1024
#define DINNER 2048
#define DSTATE 16
#define DTRANK 64
#define LSEQ 2048
#define NCHUNK 16
#define LCHUNK 128   // LSEQ/NCHUNK

typedef unsigned short ushort;
typedef __attribute__((ext_vector_type(8))) short short8;
typedef __attribute__((ext_vector_type(4))) float float4v;

__device__ inline ushort f2bf(float f) {
    __hip_bfloat16 h = __float2bfloat16(f);
    return *reinterpret_cast<ushort*>(&h);
}
__device__ inline float bf2f(ushort u) {
    union { unsigned int i; float f; } w; w.i = ((unsigned int)u) << 16; return w.f;
}

// async global->LDS DMA, 16 B/lane. lds dest = wave-uniform base + lane*16.
__device__ inline void dma16(const void* g, void* l) {
    __builtin_amdgcn_global_load_lds(
        (const __attribute__((address_space(1))) unsigned int*)g,
        (__attribute__((address_space(3))) unsigned int*)l, 16, 0, 0);
}

// ---------------- fused prep: 4 transposes + RMSNorm + dbc zero ------------
// blocks: [0,4096) in_proj^T | [4096,6144) out_proj^T | [6144,6336) x_proj^T |
// [6336,6464) dt_w^T | [6464,14656) rmsnorm rows | [14656,15424) dbc zero.
__global__ __launch_bounds__(256)
void prep_kernel(const float* __restrict__ in_proj, ushort* __restrict__ bt1,
                 const float* __restrict__ out_proj, ushort* __restrict__ bt2,
                 const float* __restrict__ x_proj, ushort* __restrict__ bt3,
                 const float* __restrict__ dt_w, ushort* __restrict__ bt4,
                 const float* __restrict__ x, const float* __restrict__ rms_w,
                 ushort* __restrict__ xn, float* __restrict__ dbc) {
    __shared__ float tld[32][33];
    __shared__ float red[4];
    int bid = blockIdx.x, tid = threadIdx.x;
    if (bid < 6464) {
        const float* in; ushort* outT; int R, C, bx, by;
        if (bid < 4096)      { in = in_proj;  outT = bt1; R = 1024; C = 4096; bx = bid & 127; by = bid >> 7; }
        else if (bid < 6144) { int t = bid - 4096; in = out_proj; outT = bt2; R = 2048; C = 1024; bx = t & 31; by = t >> 5; }
        else if (bid < 6336) { int t = bid - 6144; in = x_proj;  outT = bt3; R = 2048; C = 96;  bx = t % 3;  by = t / 3; }
        else                 { int t = bid - 6336; in = dt_w;    outT = bt4; R = 64;   C = 2048; bx = t & 63; by = t >> 6; }
        int tx = tid & 31, ty = tid >> 5;
#pragma unroll
        for (int k = 0; k < 4; ++k)
            tld[ty + k * 8][tx] = in[(long)(by * 32 + ty + k * 8) * C + bx * 32 + tx];
        __syncthreads();
#pragma unroll
        for (int k = 0; k < 4; ++k)
            outT[(long)(bx * 32 + ty + k * 8) * R + by * 32 + tx] = f2bf(tld[tx][ty + k * 8]);
    } else if (bid < 14656) {
        int row = bid - 6464;
        float4 xv = ((const float4*)(x + (long)row * DIM))[tid];
        float ss = xv.x * xv.x + xv.y * xv.y + xv.z * xv.z + xv.w * xv.w;
        for (int off = 32; off > 0; off >>= 1) ss += __shfl_down(ss, off);
        if ((tid & 63) == 0) red[tid >> 6] = ss;
        __syncthreads();
        float scale = rsqrtf((red[0] + red[1] + red[2] + red[3]) / DIM + 1e-5f);
        float4 wv = ((const float4*)rms_w)[tid];
        ushort4 ov;
        ov.x = f2bf(xv.x * scale * wv.x);
        ov.y = f2bf(xv.y * scale * wv.y);
        ov.z = f2bf(xv.z * scale * wv.z);
        ov.w = f2bf(xv.w * scale * wv.w);
        ((ushort4*)xn)[(long)row * 256 + tid] = ov;
    } else {
        int idx = (bid - 14656) * 256 + tid;
        float4 z = {0.f, 0.f, 0.f, 0.f};
        ((float4*)dbc)[idx] = z;   // 768*256*4 = 786432 floats
    }
}

// ---------------- DMA-staged bf16 MFMA GEMM (m97 structure) ----------------
// C[M,N] = A[M,K] @ B[K,N]; A bf16 [M][lda], Bt = B^T bf16 [N][ldbt].
// 128x128 tile, BK=32, 256 thr = 4 waves (2x2), wave does 4x4 of 16x16x32.
// EPI: 0 = bf16 store; 2 = acc + aux[row*ldc+col] -> f32 (residual).
template <int EPI>
__global__ __launch_bounds__(256)
void mfma_gemm_dma(const ushort* __restrict__ A, int lda,
                   const ushort* __restrict__ Bt, int ldbt,
                   void* __restrict__ Cv, int ldc, int K,
                   const float* __restrict__ aux) {
    __shared__ __align__(16) ushort As[128][32];
    __shared__ __align__(16) ushort Bs[128][32];
    int tid = threadIdx.x;
    int wave = tid >> 6, lane = tid & 63;
    int wm = wave >> 1, wn = wave & 1;
    int quad = lane >> 4, l16 = lane & 15;
    int row0 = blockIdx.y * 128, col0 = blockIdx.x * 128;

    int r0 = (wave * 2 + 0) * 16 + (lane >> 2);
    int r1 = (wave * 2 + 1) * 16 + (lane >> 2);
    int ks = (lane & 3) * 8;
    const ushort* a0 = A + (long)(row0 + r0) * lda + ks;
    const ushort* a1 = A + (long)(row0 + r1) * lda + ks;
    const ushort* b0 = Bt + (long)(col0 + r0) * ldbt + ks;
    const ushort* b1 = Bt + (long)(col0 + r1) * ldbt + ks;
    ushort* lA0 = &As[(wave * 2 + 0) * 16][0];
    ushort* lA1 = &As[(wave * 2 + 1) * 16][0];
    ushort* lB0 = &Bs[(wave * 2 + 0) * 16][0];
    ushort* lB1 = &Bs[(wave * 2 + 1) * 16][0];

    float4v acc[4][4] = {};

    for (int k0 = 0; k0 < K; k0 += 32) {
        dma16(a0 + k0, lA0);
        dma16(a1 + k0, lA1);
        dma16(b0 + k0, lB0);
        dma16(b1 + k0, lB1);
        __syncthreads();

        short8 afrag[4], bfrag[4];
#pragma unroll
        for (int i = 0; i < 4; ++i)
            afrag[i] = *reinterpret_cast<const short8*>(&As[wm * 64 + i * 16 + l16][quad * 8]);
#pragma unroll
        for (int j = 0; j < 4; ++j)
            bfrag[j] = *reinterpret_cast<const short8*>(&Bs[wn * 64 + j * 16 + l16][quad * 8]);
#pragma unroll
        for (int i = 0; i < 4; ++i)
#pragma unroll
            for (int j = 0; j < 4; ++j)
                acc[i][j] = __builtin_amdgcn_mfma_f32_16x16x32_bf16(
                    afrag[i], bfrag[j], acc[i][j], 0, 0, 0);
        __syncthreads();
    }

#pragma unroll
    for (int i = 0; i < 4; ++i) {
#pragma unroll
        for (int j = 0; j < 4; ++j) {
            int rbase = row0 + wm * 64 + i * 16 + quad * 4;
            int c = col0 + wn * 64 + j * 16 + l16;
#pragma unroll
            for (int r = 0; r < 4; ++r) {
                float v = acc[i][j][r];
                long idx = (long)(rbase + r) * ldc + c;
                if (EPI == 2) ((float*)Cv)[idx] = v + aux[idx];
                else          ((ushort*)Cv)[idx] = f2bf(v);
            }
        }
    }
}

// ------- x_proj GEMM with conv+silu fused into A-staging, split-K ----------
// dbc[8192][96] += silu(conv(xi)) @ x_proj. grid (4 k-splits, 64 row tiles).
// A-tile [128][32ch] computed on the fly from xz xi-cols; B DMA from bt3
// (rows >=96 are garbage -> cols >=96 discarded at store).
__global__ __launch_bounds__(256)
void xproj_conv_gemm(const ushort* __restrict__ xz,
                     const float* __restrict__ cw, const float* __restrict__ cb,
                     const ushort* __restrict__ bt3,   // [128][2048]
                     float* __restrict__ dbc) {
    __shared__ __align__(16) ushort As[128][32];
    __shared__ __align__(16) ushort Bs[128][32];
    int tid = threadIdx.x;
    int wave = tid >> 6, lane = tid & 63;
    int wm = wave >> 1, wn = wave & 1;
    int quad = lane >> 4, l16 = lane & 15;
    int row0 = blockIdx.y * 128;
    int ks0 = blockIdx.x * 512;
    int srow = tid >> 2, sseg = tid & 3;

    int r0 = (wave * 2 + 0) * 16 + (lane >> 2);
    int r1 = (wave * 2 + 1) * 16 + (lane >> 2);
    int ksl = (lane & 3) * 8;
    const ushort* b0 = bt3 + (long)r0 * 2048 + ks0 + ksl;
    const ushort* b1 = bt3 + (long)r1 * 2048 + ks0 + ksl;
    ushort* lB0 = &Bs[(wave * 2 + 0) * 16][0];
    ushort* lB1 = &Bs[(wave * 2 + 1) * 16][0];

    float4v acc[4][4] = {};

    for (int k0 = 0; k0 < 512; k0 += 32) {
        dma16(b0 + k0, lB0);
        dma16(b1 + k0, lB1);
#pragma unroll
        for (int it = 0; it < 2; ++it) {
            int r = srow + it * 64;
            long row = row0 + r;
            int l = (int)(row & (LSEQ - 1));
            int cch = ks0 + k0 + sseg * 8;
            short8 v[4];
#pragma unroll
            for (int t = 0; t < 4; ++t) {
                if (l - 3 + t >= 0) v[t] = *(const short8*)&xz[(row - 3 + t) * 4096 + cch];
                else { short8 zz = {0,0,0,0,0,0,0,0}; v[t] = zz; }
            }
            ushort o[8];
#pragma unroll
            for (int j = 0; j < 8; ++j) {
                float4 w = ((const float4*)cw)[cch + j];
                float a = cb[cch + j]
                        + bf2f((ushort)v[0][j]) * w.x + bf2f((ushort)v[1][j]) * w.y
                        + bf2f((ushort)v[2][j]) * w.z + bf2f((ushort)v[3][j]) * w.w;
                a = a / (1.f + __expf(-a));
                o[j] = f2bf(a);
            }
            *(short8*)&As[r][sseg * 8] = *(const short8*)o;
        }
        __syncthreads();

        short8 afrag[4], bfrag[4];
#pragma unroll
        for (int i = 0; i < 4; ++i)
            afrag[i] = *reinterpret_cast<const short8*>(&As[wm * 64 + i * 16 + l16][quad * 8]);
#pragma unroll
        for (int j = 0; j < 4; ++j)
            bfrag[j] = *reinterpret_cast<const short8*>(&Bs[wn * 64 + j * 16 + l16][quad * 8]);
#pragma unroll
        for (int i = 0; i < 4; ++i)
#pragma unroll
            for (int j = 0; j < 4; ++j)
                acc[i][j] = __builtin_amdgcn_mfma_f32_16x16x32_bf16(
                    afrag[i], bfrag[j], acc[i][j], 0, 0, 0);
        __syncthreads();
    }
#pragma unroll
    for (int i = 0; i < 4; ++i) {
#pragma unroll
        for (int j = 0; j < 4; ++j) {
            int rbase = row0 + wm * 64 + i * 16 + quad * 4;
            int c = wn * 64 + j * 16 + l16;
            if (c < 96) {
#pragma unroll
                for (int r = 0; r < 4; ++r)
                    atomicAdd(&dbc[(long)(rbase + r) * 96 + c], acc[i][j][r]);
            }
        }
    }
}

// ---------------- VALU-staged MFMA GEMM for dt (A fp32, K=64) ----------------
// dlt = softplus(dbc[:, :64] @ dt_w + dt_b) -> bf16 [8192][2048].
__global__ __launch_bounds__(256)
void mfma_gemm_dt(const float* __restrict__ A, int lda,
                  const ushort* __restrict__ Bt, int ldbt,
                  ushort* __restrict__ C, int ldc, int K,
                  const float* __restrict__ aux) {
    __shared__ __align__(16) ushort As[128][40];
    __shared__ __align__(16) ushort Bs[128][40];
    int tid = threadIdx.x;
    int wave = tid >> 6, lane = tid & 63;
    int wm = wave >> 1, wn = wave & 1;
    int quad = lane >> 4, l16 = lane & 15;
    int row0 = blockIdx.y * 128, col0 = blockIdx.x * 128;
    int srow = tid >> 2, sseg = tid & 3;

    float4v acc[4][4] = {};

    for (int k0 = 0; k0 < K; k0 += 32) {
#pragma unroll
        for (int it = 0; it < 2; ++it) {
            int r = srow + it * 64;
            const float* ap = A + (long)(row0 + r) * lda + k0 + sseg * 8;
            ushort tmp[8];
#pragma unroll
            for (int j = 0; j < 8; ++j) tmp[j] = f2bf(ap[j]);
            *reinterpret_cast<short8*>(&As[r][sseg * 8]) =
                *reinterpret_cast<const short8*>(tmp);
            const ushort* bp = Bt + (long)(col0 + r) * ldbt + k0 + sseg * 8;
            *reinterpret_cast<short8*>(&Bs[r][sseg * 8]) =
                *reinterpret_cast<const short8*>(bp);
        }
        __syncthreads();
        short8 afrag[4], bfrag[4];
#pragma unroll
        for (int i = 0; i < 4; ++i)
            afrag[i] = *reinterpret_cast<const short8*>(&As[wm * 64 + i * 16 + l16][quad * 8]);
#pragma unroll
        for (int j = 0; j < 4; ++j)
            bfrag[j] = *reinterpret_cast<const short8*>(&Bs[wn * 64 + j * 16 + l16][quad * 8]);
#pragma unroll
        for (int i = 0; i < 4; ++i)
#pragma unroll
            for (int j = 0; j < 4; ++j)
                acc[i][j] = __builtin_amdgcn_mfma_f32_16x16x32_bf16(
                    afrag[i], bfrag[j], acc[i][j], 0, 0, 0);
        __syncthreads();
    }
#pragma unroll
    for (int i = 0; i < 4; ++i) {
#pragma unroll
        for (int j = 0; j < 4; ++j) {
            int rbase = row0 + wm * 64 + i * 16 + quad * 4;
            int c = col0 + wn * 64 + j * 16 + l16;
#pragma unroll
            for (int r = 0; r < 4; ++r) {
                float v = acc[i][j][r] + aux[c];
                v = (v > 20.f) ? v : log1pf(expf(v));
                C[(long)(rbase + r) * ldc + c] = f2bf(v);
            }
        }
    }
}

// ---------------- chunked selective scan, conv fused -----------------------
// thread = (b,c). conv computed via rolling 3-tap window over xz xi-cols.
// part1: chunk-local scan from h=0; emit chunk-end h[16] and sum(d).
__global__ __launch_bounds__(256)
void scan_part1(const ushort* __restrict__ xz,     // xi at row*4096 + c
                const ushort* __restrict__ dlt,    // delta [8192][2048]
                const float* __restrict__ dbc,     // [ROWS][96]: dt|B|C
                const float* __restrict__ A_log,
                const float* __restrict__ cw, const float* __restrict__ cb,
                float* __restrict__ hbuf,          // [B][G][16][2048]
                float* __restrict__ sdbuf) {       // [B][G][2048]
    int c = blockIdx.y * 256 + threadIdx.x;
    int b = blockIdx.z, g = blockIdx.x;
    float A[16];
#pragma unroll
    for (int s = 0; s < 16; ++s) A[s] = -__expf(A_log[c * 16 + s]);
    float4 w = ((const float4*)cw)[c];
    float cbc = cb[c];
    float h[16] = {};
    float sumd = 0.f;
    long row0 = (long)b * LSEQ + (long)g * LCHUNK;
    int l0 = g * LCHUNK;
    float x0 = (l0 >= 3) ? bf2f(xz[(row0 - 3) * 4096 + c]) : 0.f;
    float x1 = (l0 >= 2) ? bf2f(xz[(row0 - 2) * 4096 + c]) : 0.f;
    float x2 = (l0 >= 1) ? bf2f(xz[(row0 - 1) * 4096 + c]) : 0.f;
    long row = row0;
    for (int l = 0; l < LCHUNK; ++l, ++row) {
        float x3 = bf2f(xz[row * 4096 + c]);
        float xc = cbc + x0 * w.x + x1 * w.y + x2 * w.z + x3 * w.w;
        xc = xc / (1.f + __expf(-xc));
        x0 = x1; x1 = x2; x2 = x3;
        float d = bf2f(dlt[row * 2048 + c]);
        const float* __restrict__ bc = dbc + row * 96;
        sumd += d;
        float dx = d * xc;
#pragma unroll
        for (int s = 0; s < 16; ++s)
            h[s] = __expf(d * A[s]) * h[s] + dx * bc[64 + s];
    }
    long hb = ((long)(b * NCHUNK + g) * 16) * 2048 + c;
#pragma unroll
    for (int s = 0; s < 16; ++s) hbuf[hb + (long)s * 2048] = h[s];
    sdbuf[(long)(b * NCHUNK + g) * 2048 + c] = sumd;
}

// part2: serial combine over chunks; hbuf becomes h_in per chunk.
__global__ __launch_bounds__(256)
void scan_part2(float* __restrict__ hbuf, const float* __restrict__ sdbuf,
                const float* __restrict__ A_log) {
    int gl = blockIdx.x * 256 + threadIdx.x;   // 131072 threads
    int c = gl & 2047, s = (gl >> 11) & 15, b = gl >> 15;
    float A = -__expf(A_log[c * 16 + s]);
    float hrun = 0.f;
    for (int g = 0; g < NCHUNK; ++g) {
        long hi = ((long)(b * NCHUNK + g) * 16 + s) * 2048 + c;
        float hout = hbuf[hi];
        float sd = sdbuf[(long)(b * NCHUNK + g) * 2048 + c];
        hbuf[hi] = hrun;
        hrun = __expf(A * sd) * hrun + hout;
    }
}

// part3: re-scan from h_in; y = sum_s h*C; D-skip + SiLU gate; y -> dlt (bf16).
__global__ __launch_bounds__(256)
void scan_part3(const ushort* __restrict__ xz,    // xi + z halves (read-only)
                ushort* __restrict__ dlt,         // delta in / gated y out
                const float* __restrict__ dbc,
                const float* __restrict__ A_log,
                const float* __restrict__ cw, const float* __restrict__ cb,
                const float* __restrict__ Dp,
                const float* __restrict__ hbuf) {
    int c = blockIdx.y * 256 + threadIdx.x;
    int b = blockIdx.z, g = blockIdx.x;
    float A[16], h[16];
#pragma unroll
    for (int s = 0; s < 16; ++s) A[s] = -__expf(A_log[c * 16 + s]);
    long hb = ((long)(b * NCHUNK + g) * 16) * 2048 + c;
#pragma unroll
    for (int s = 0; s < 16; ++s) h[s] = hbuf[hb + (long)s * 2048];
    float4 w = ((const float4*)cw)[c];
    float cbc = cb[c];
    float Dc = Dp[c];
    long row0 = (long)b * LSEQ + (long)g * LCHUNK;
    int l0 = g * LCHUNK;
    float x0 = (l0 >= 3) ? bf2f(xz[(row0 - 3) * 4096 + c]) : 0.f;
    float x1 = (l0 >= 2) ? bf2f(xz[(row0 - 2) * 4096 + c]) : 0.f;
    float x2 = (l0 >= 1) ? bf2f(xz[(row0 - 1) * 4096 + c]) : 0.f;
    long row = row0;
    for (int l = 0; l < LCHUNK; ++l, ++row) {
        float x3 = bf2f(xz[row * 4096 + c]);
        float xc = cbc + x0 * w.x + x1 * w.y + x2 * w.z + x3 * w.w;
        xc = xc / (1.f + __expf(-xc));
        x0 = x1; x1 = x2; x2 = x3;
        float d = bf2f(dlt[row * 2048 + c]);
        float z = bf2f(xz[row * 4096 + 2048 + c]);
        const float* __restrict__ bc = dbc + row * 96;
        float dx = d * xc;
        float y = 0.f;
#pragma unroll
        for (int s = 0; s < 16; ++s) {
            h[s] = __expf(d * A[s]) * h[s] + dx * bc[64 + s];
            y += h[s] * bc[80 + s];
        }
        float yv = (y + xc * Dc) * (z / (1.f + __expf(-z)));
        dlt[row * 2048 + c] = f2bf(yv);
    }
}

extern "C" void kernel_launch(void* const* d_in, const int* in_sizes, int n_in,
                              void* d_out, int out_size, void* d_ws, size_t ws_size,
                              hipStream_t stream) {
    const float* x        = (const float*)d_in[0];
    const float* rms_w    = (const float*)d_in[1];
    const float* in_proj  = (const float*)d_in[2];
    const float* conv_w   = (const float*)d_in[3];
    const float* conv_b   = (const float*)d_in[4];
    const float* x_proj   = (const float*)d_in[5];
    const float* dt_w     = (const float*)d_in[6];
    const float* dt_b     = (const float*)d_in[7];
    const float* A_log    = (const float*)d_in[8];
    const float* Dp       = (const float*)d_in[9];
    const float* out_proj = (const float*)d_in[10];
    float* out = (float*)d_out;

    char* p = (char*)d_ws;
    ushort* xz  = (ushort*)p;   p += (size_t)ROWS * 4096 * 2;   // 64 MB  xi|z
    ushort* dlt = (ushort*)p;   p += (size_t)ROWS * 2048 * 2;   // 32 MB  delta -> gated y
    float*  dbc = (float*)p;    p += (size_t)ROWS * 96 * 4;     // 3 MB
    ushort* bt1 = (ushort*)p;   p += (size_t)4096 * 1024 * 2;   // 8 MB   in_proj^T
    ushort* bt2 = (ushort*)p;   p += (size_t)1024 * 2048 * 2;   // 4 MB   out_proj^T
    ushort* bt3 = (ushort*)p;   p += (size_t)128 * 2048 * 2;    // 512 KB x_proj^T (96 rows valid)
    ushort* bt4 = (ushort*)p;   p += (size_t)2048 * 64 * 2;     // 256 KB dt_w^T
    ushort* xn  = (ushort*)p;   p += (size_t)ROWS * 1024 * 2;   // 16 MB  (dead after in_proj)
    float* hbuf  = (float*)xn;                                  // 8 MB   overlay on xn
    float* sdbuf = (float*)xn + (size_t)4 * NCHUNK * 16 * 2048; // 512 KB overlay on xn
    // total ~127.8 MiB

    // 1. prep: weight transposes + RMSNorm -> xn bf16 + dbc zero
    prep_kernel<<<15424, 256, 0, stream>>>(in_proj, bt1, out_proj, bt2,
                                           x_proj, bt3, dt_w, bt4,
                                           x, rms_w, xn, dbc);
    // 2. xz = xn @ in_proj  [8192,1024]@[1024,4096] -> bf16 (DMA MFMA)
    mfma_gemm_dma<0><<<dim3(4096 / 128, ROWS / 128), 256, 0, stream>>>(
        xn, DIM, bt1, 1024, xz, 4096, DIM, nullptr);
    // 3. dbc += silu(conv(xi)) @ x_proj  (fused conv, split-K x4, atomics)
    xproj_conv_gemm<<<dim3(4, ROWS / 128), 256, 0, stream>>>(
        xz, conv_w, conv_b, bt3, dbc);
    // 4. dlt = softplus(dbc[:,:64] @ dt_w + dt_b) -> bf16
    mfma_gemm_dt<<<dim3(2048 / 128, ROWS / 128), 256, 0, stream>>>(
        dbc, 96, bt4, 64, dlt, 2048, DTRANK, dt_b);
    // 5-7. chunked selective scan (conv recomputed via rolling window)
    scan_part1<<<dim3(NCHUNK, DINNER / 256, 4), 256, 0, stream>>>(
        xz, dlt, dbc, A_log, conv_w, conv_b, hbuf, sdbuf);
    scan_part2<<<512, 256, 0, stream>>>(hbuf, sdbuf, A_log);
    scan_part3<<<dim3(NCHUNK, DINNER / 256, 4), 256, 0, stream>>>(
        xz, dlt, dbc, A_log, conv_w, conv_b, Dp, hbuf);
    // 8. out = x + y @ out_proj  [8192,2048]@[2048,1024] -> f32 (DMA MFMA)
    mfma_gemm_dma<2><<<dim3(DIM / 128, ROWS / 128), 256, 0, stream>>>(
        dlt, 2048, bt2, DINNER, out, DIM, DINNER, x);
}